// Round 1
// baseline (888.177 us; speedup 1.0000x reference)
//
#include <hip/hip_runtime.h>
#include <hip/hip_bf16.h>
#include <stdint.h>

#define NROWS   65536
#define F_IN    256
#define H1_DIM  512
#define H2_DIM  512
#define LAT     256
#define EPS     1e-5f
#define BM      64
#define NBLK    (NROWS / BM)   // 1024

typedef __attribute__((ext_vector_type(8))) short short8;
typedef __attribute__((ext_vector_type(4))) float f32x4;

__device__ __forceinline__ unsigned short f2bf(float f) {
    unsigned u = __float_as_uint(f);
    unsigned r = (u + 0x7FFFu + ((u >> 16) & 1u)) >> 16;
    return (unsigned short)r;
}

// ---------------- K0: weight transpose + bf16 convert ----------------
// W1 [256][512] -> w1t [512][256]; W2 [512][512] -> w2t [512][512];
// W3 [512][256] -> w3t [256][512]   (all [N][K] bf16)
__global__ void k_prep(const float* __restrict__ W1, const float* __restrict__ W2,
                       const float* __restrict__ W3,
                       unsigned short* __restrict__ w1t, unsigned short* __restrict__ w2t,
                       unsigned short* __restrict__ w3t) {
    int idx = blockIdx.x * 256 + threadIdx.x;
    if (idx < 131072) {
        int n = idx >> 8, k = idx & 255;
        w1t[idx] = f2bf(W1[k * 512 + n]);
    } else if (idx < 393216) {
        int j = idx - 131072, n = j >> 9, k = j & 511;
        w2t[j] = f2bf(W2[k * 512 + n]);
    } else if (idx < 524288) {
        int j = idx - 393216, n = j >> 9, k = j & 511;
        w3t[j] = f2bf(W3[k * 256 + n]);
    }
}

// ---------------- K1: fused MLP chain ----------------
// grid 1024 blocks x 512 thr (8 waves). Block owns 64 batch rows.
// LDS h1s: 64 KB, k-packed cells: cell(kg, r) at elem (kg*64+r)*8, kg = k>>3.
// First 4 KB aliased as the streamed e-slice buffer during layer1 K-loop.
__global__ __launch_bounds__(512, 2)
void k_fused(const float* __restrict__ x,
             const unsigned short* __restrict__ w1t,
             const unsigned short* __restrict__ w2t,
             const unsigned short* __restrict__ w3t,
             const float* __restrict__ b1, const float* __restrict__ b2,
             const float* __restrict__ b3,
             float* __restrict__ out,
             float* __restrict__ psum, float* __restrict__ psumsq) {
    __shared__ unsigned short h1s[64 * 512];   // 65536 B

    const int tid = threadIdx.x;
    const int w   = tid >> 6;
    const int l   = tid & 63;
    const int l15 = l & 15;
    const int lg  = l >> 4;       // 0..3
    const int blk = blockIdx.x;
    const int row0 = blk * BM;

    // producer mapping (threads 0..255): r = tid&63, kg = tid>>6 (LDS conflict-free)
    const int pr  = tid & 63;
    const int pkg = (tid >> 6) & 3;
    const bool producer = (tid < 256);
    const float* xrow = x + (size_t)(row0 + pr) * 768;

    float agg[4][4][4];
#pragma unroll
    for (int a = 0; a < 4; ++a)
#pragma unroll
        for (int b = 0; b < 4; ++b)
#pragma unroll
            for (int c = 0; c < 4; ++c) agg[a][b][c] = 0.f;

    for (int e = 0; e < 3; ++e) {
        const int na = e >> 1;            // 0,0,1
        const int nb = ((e + 1) >> 1) + 1; // 1,2,2

        f32x4 c1[4][4];
#pragma unroll
        for (int mt = 0; mt < 4; ++mt)
#pragma unroll
            for (int nt = 0; nt < 4; ++nt) c1[mt][nt] = (f32x4){0.f, 0.f, 0.f, 0.f};

        // prefetch k-slice 0
        float4 pa0, pa1, pb0, pb1;
        if (producer) {
            const float* pna = xrow + na * 256 + pkg * 8;
            const float* pnb = xrow + nb * 256 + pkg * 8;
            pa0 = *(const float4*)(pna);     pa1 = *(const float4*)(pna + 4);
            pb0 = *(const float4*)(pnb);     pb1 = *(const float4*)(pnb + 4);
        }

        for (int kt = 0; kt < 8; ++kt) {
            __syncthreads();   // previous readers of e-slice done (also protects h1s tail from prev edge)
            if (producer) {
                uint4 pk;
                pk.x = (unsigned)f2bf(pa0.x + pb0.x) | ((unsigned)f2bf(pa0.y + pb0.y) << 16);
                pk.y = (unsigned)f2bf(pa0.z + pb0.z) | ((unsigned)f2bf(pa0.w + pb0.w) << 16);
                pk.z = (unsigned)f2bf(pa1.x + pb1.x) | ((unsigned)f2bf(pa1.y + pb1.y) << 16);
                pk.w = (unsigned)f2bf(pa1.z + pb1.z) | ((unsigned)f2bf(pa1.w + pb1.w) << 16);
                *(uint4*)(&h1s[(pkg * 64 + pr) * 8]) = pk;
            }
            __syncthreads();
            if (producer && kt < 7) {       // prefetch next slice; latency hides under MFMA
                int k0 = (kt + 1) * 32 + pkg * 8;
                const float* pna = xrow + na * 256 + k0;
                const float* pnb = xrow + nb * 256 + k0;
                pa0 = *(const float4*)(pna);  pa1 = *(const float4*)(pna + 4);
                pb0 = *(const float4*)(pnb);  pb1 = *(const float4*)(pnb + 4);
            }
            short8 afr[4];
#pragma unroll
            for (int mt = 0; mt < 4; ++mt)
                afr[mt] = *(const short8*)(&h1s[(lg * 64 + mt * 16 + l15) * 8]);
#pragma unroll
            for (int nt = 0; nt < 4; ++nt) {
                int n = w * 64 + nt * 16 + l15;
                short8 bfr = *(const short8*)(w1t + n * 256 + kt * 32 + lg * 8);
#pragma unroll
                for (int mt = 0; mt < 4; ++mt)
                    c1[mt][nt] = __builtin_amdgcn_mfma_f32_16x16x32_bf16(afr[mt], bfr, c1[mt][nt], 0, 0, 0);
            }
        }

        // layer1 epilogue: relu(c1 + b1) -> h1s (k-packed). Wave w owns kg in [w*8, w*8+8).
        __syncthreads();
#pragma unroll
        for (int nt = 0; nt < 4; ++nt) {
            int c = w * 64 + nt * 16 + l15;
            float bias = b1[c];
#pragma unroll
            for (int mt = 0; mt < 4; ++mt)
#pragma unroll
                for (int reg = 0; reg < 4; ++reg) {
                    int r = mt * 16 + lg * 4 + reg;
                    float v = c1[mt][nt][reg] + bias;
                    v = v > 0.f ? v : 0.f;
                    h1s[((c >> 3) * 64 + r) * 8 + (c & 7)] = f2bf(v);
                }
        }
        __syncthreads();

        // layer2: c2 = h1 @ W2 (K = 512, 16 K-steps), no barriers inside
        f32x4 c2[4][4];
#pragma unroll
        for (int mt = 0; mt < 4; ++mt)
#pragma unroll
            for (int nt = 0; nt < 4; ++nt) c2[mt][nt] = (f32x4){0.f, 0.f, 0.f, 0.f};

        for (int kt = 0; kt < 16; ++kt) {
            short8 afr[4];
#pragma unroll
            for (int mt = 0; mt < 4; ++mt)
                afr[mt] = *(const short8*)(&h1s[((kt * 4 + lg) * 64 + mt * 16 + l15) * 8]);
#pragma unroll
            for (int nt = 0; nt < 4; ++nt) {
                int n = w * 64 + nt * 16 + l15;
                short8 bfr = *(const short8*)(w2t + n * 512 + kt * 32 + lg * 8);
#pragma unroll
                for (int mt = 0; mt < 4; ++mt)
                    c2[mt][nt] = __builtin_amdgcn_mfma_f32_16x16x32_bf16(afr[mt], bfr, c2[mt][nt], 0, 0, 0);
            }
        }

        // relu + b2, accumulate into agg (registers)
#pragma unroll
        for (int nt = 0; nt < 4; ++nt) {
            float bias = b2[w * 64 + nt * 16 + l15];
#pragma unroll
            for (int mt = 0; mt < 4; ++mt)
#pragma unroll
                for (int reg = 0; reg < 4; ++reg) {
                    float v = c2[mt][nt][reg] + bias;
                    agg[mt][nt][reg] += (v > 0.f ? v : 0.f);
                }
        }
        // next edge's first __syncthreads() protects h1s reuse
    }

    // write agg -> h1s (bf16 k-packed)
    __syncthreads();
#pragma unroll
    for (int nt = 0; nt < 4; ++nt) {
        int c = w * 64 + nt * 16 + l15;
#pragma unroll
        for (int mt = 0; mt < 4; ++mt)
#pragma unroll
            for (int reg = 0; reg < 4; ++reg) {
                int r = mt * 16 + lg * 4 + reg;
                h1s[((c >> 3) * 64 + r) * 8 + (c & 7)] = f2bf(agg[mt][nt][reg]);
            }
    }
    __syncthreads();

    // layer3: z = agg @ W3 + b3. Wave owns 32 output cols.
    f32x4 c3[4][2];
#pragma unroll
    for (int mt = 0; mt < 4; ++mt)
#pragma unroll
        for (int nt = 0; nt < 2; ++nt) c3[mt][nt] = (f32x4){0.f, 0.f, 0.f, 0.f};

    for (int kt = 0; kt < 16; ++kt) {
        short8 afr[4];
#pragma unroll
        for (int mt = 0; mt < 4; ++mt)
            afr[mt] = *(const short8*)(&h1s[((kt * 4 + lg) * 64 + mt * 16 + l15) * 8]);
#pragma unroll
        for (int nt = 0; nt < 2; ++nt) {
            int n = w * 32 + nt * 16 + l15;
            short8 bfr = *(const short8*)(w3t + n * 512 + kt * 32 + lg * 8);
#pragma unroll
            for (int mt = 0; mt < 4; ++mt)
                c3[mt][nt] = __builtin_amdgcn_mfma_f32_16x16x32_bf16(afr[mt], bfr, c3[mt][nt], 0, 0, 0);
        }
    }

    // epilogue: z store (unnormalized) + per-feature partial sums
#pragma unroll
    for (int nt = 0; nt < 2; ++nt) {
        int c = w * 32 + nt * 16 + l15;
        float bias = b3[c];
        float s = 0.f, q = 0.f;
#pragma unroll
        for (int mt = 0; mt < 4; ++mt)
#pragma unroll
            for (int reg = 0; reg < 4; ++reg) {
                int r = mt * 16 + lg * 4 + reg;
                float v = c3[mt][nt][reg] + bias;
                out[(size_t)(row0 + r) * 256 + c] = v;
                s += v;
                q += v * v;
            }
        s += __shfl_xor(s, 16); s += __shfl_xor(s, 32);
        q += __shfl_xor(q, 16); q += __shfl_xor(q, 32);
        if (lg == 0) {
            psum[c * NBLK + blk] = s;
            psumsq[c * NBLK + blk] = q;
        }
    }
}

// ---------------- K2: reduce partials -> scale/shift ----------------
__global__ void k_stats(const float* __restrict__ psum, const float* __restrict__ psumsq,
                        const float* __restrict__ gamma, const float* __restrict__ beta,
                        float* __restrict__ scale, float* __restrict__ shift) {
    int f = blockIdx.x, t = threadIdx.x;
    const float* ps = psum + f * NBLK;
    const float* pq = psumsq + f * NBLK;
    float s = ps[t] + ps[t + 256] + ps[t + 512] + ps[t + 768];
    float q = pq[t] + pq[t + 256] + pq[t + 512] + pq[t + 768];
#pragma unroll
    for (int o = 32; o > 0; o >>= 1) {
        s += __shfl_down(s, o);
        q += __shfl_down(q, o);
    }
    __shared__ float ls[4], lq[4];
    if ((t & 63) == 0) { ls[t >> 6] = s; lq[t >> 6] = q; }
    __syncthreads();
    if (t == 0) {
        s = ls[0] + ls[1] + ls[2] + ls[3];
        q = lq[0] + lq[1] + lq[2] + lq[3];
        float mu  = s * (1.f / 65536.f);
        float var = q * (1.f / 65536.f) - mu * mu;
        float sc  = gamma[f] * rsqrtf(var + EPS);
        scale[f] = sc;
        shift[f] = beta[f] - mu * sc;
    }
}

// ---------------- K3: in-place normalize of d_out ----------------
__global__ void k_norm(float4* __restrict__ out4, const float4* __restrict__ scale4,
                       const float4* __restrict__ shift4, int n4) {
    int i = blockIdx.x * blockDim.x + threadIdx.x;
    int stride = gridDim.x * blockDim.x;
    for (; i < n4; i += stride) {
        float4 v = out4[i];
        float4 sc = scale4[i & 63];
        float4 sh = shift4[i & 63];
        v.x = v.x * sc.x + sh.x;
        v.y = v.y * sc.y + sh.y;
        v.z = v.z * sc.z + sh.z;
        v.w = v.w * sc.w + sh.w;
        out4[i] = v;
    }
}

extern "C" void kernel_launch(void* const* d_in, const int* in_sizes, int n_in,
                              void* d_out, int out_size, void* d_ws, size_t ws_size,
                              hipStream_t stream) {
    const float* x     = (const float*)d_in[0];
    const float* W1    = (const float*)d_in[1];
    const float* b1    = (const float*)d_in[2];
    const float* W2    = (const float*)d_in[3];
    const float* b2    = (const float*)d_in[4];
    const float* W3    = (const float*)d_in[5];
    const float* b3    = (const float*)d_in[6];
    const float* gamma = (const float*)d_in[7];
    const float* beta  = (const float*)d_in[8];

    char* ws = (char*)d_ws;
    unsigned short* w1t = (unsigned short*)(ws);            // 262144 B
    unsigned short* w2t = (unsigned short*)(ws + 262144);   // 524288 B
    unsigned short* w3t = (unsigned short*)(ws + 786432);   // 262144 B
    float* psum   = (float*)(ws + 1048576);                 // 1 MB
    float* psumsq = (float*)(ws + 2097152);                 // 1 MB
    float* scale  = (float*)(ws + 3145728);                 // 1 KB
    float* shift  = (float*)(ws + 3146752);                 // 1 KB

    float* out = (float*)d_out;

    k_prep<<<2048, 256, 0, stream>>>(W1, W2, W3, w1t, w2t, w3t);
    k_fused<<<NBLK, 512, 0, stream>>>(x, w1t, w2t, w3t, b1, b2, b3, out, psum, psumsq);
    k_stats<<<256, 256, 0, stream>>>(psum, psumsq, gamma, beta, scale, shift);
    k_norm<<<2048, 256, 0, stream>>>((float4*)out, (const float4*)scale, (const float4*)shift,
                                     (NROWS * 256) / 4);
}